// Round 1
// baseline (1170.265 us; speedup 1.0000x reference)
//
#include <hip/hip_runtime.h>
#include <stdint.h>

#define N_NODES 50000
#define N_EDGES 600000
#define D       128
#define EPS     1e-5f

// ---------------------------------------------------------------------------
// edge dtype detection: reference says int64, harness doc hints int32.
// If int64: high 32-bit word of every value (< 50000, nonneg) is 0.
// If int32: odd-index entries are random indices; all-zero over 128 samples
// has probability (1/50000)^128 ~ 0.
// ---------------------------------------------------------------------------
__global__ void detect_idx64(const unsigned int* e, int* flag) {
    if (blockIdx.x == 0 && threadIdx.x == 0) {
        int is64 = 1;
        for (int i = 0; i < 128; ++i)
            if (e[2 * i + 1] != 0u) { is64 = 0; break; }
        *flag = is64;
    }
}

__device__ __forceinline__ int load_idx(const void* e, long long i, int is64) {
    return is64 ? (int)((const long long*)e)[i] : ((const int*)e)[i];
}

// ---------------------------------------------------------------------------
// degree counting (u32 atomics)
// ---------------------------------------------------------------------------
__global__ __launch_bounds__(256) void deg_kernel(const void* edges,
                                                  unsigned int* deg_out,
                                                  unsigned int* deg_in,
                                                  const int* flag) {
    int is64 = *flag;
    int i = blockIdx.x * blockDim.x + threadIdx.x;
    if (i < N_EDGES) {
        int s = load_idx(edges, i, is64);
        int d = load_idx(edges, (long long)N_EDGES + i, is64);
        atomicAdd(&deg_out[s], 1u);
        atomicAdd(&deg_in[d], 1u);
    }
}

// in-place convert u32 degree -> f32 rsqrt(max(deg,1))
__global__ __launch_bounds__(256) void inv_sqrt_kernel(unsigned int* deg_out,
                                                       unsigned int* deg_in) {
    int i = blockIdx.x * blockDim.x + threadIdx.x;
    if (i < N_NODES) {
        float o = (float)(deg_out[i] > 1u ? deg_out[i] : 1u);
        float g = (float)(deg_in[i]  > 1u ? deg_in[i]  : 1u);
        ((float*)deg_out)[i] = rsqrtf(o);
        ((float*)deg_in)[i]  = rsqrtf(g);
    }
}

// ---------------------------------------------------------------------------
// LayerNorm: one wave (64 lanes) per row, 2 elems/lane
// ---------------------------------------------------------------------------
__global__ __launch_bounds__(256) void ln_kernel(const float* __restrict__ h,
                                                 const float* __restrict__ gamma,
                                                 const float* __restrict__ beta,
                                                 float* __restrict__ hn) {
    int wid  = threadIdx.x >> 6;
    int lane = threadIdx.x & 63;
    int row  = blockIdx.x * 4 + wid;
    if (row >= N_NODES) return;
    const float* x = h + (long long)row * D;
    float a = x[lane];
    float c = x[lane + 64];
    float s  = a + c;
    float ss = a * a + c * c;
    #pragma unroll
    for (int off = 32; off; off >>= 1) {
        s  += __shfl_xor(s,  off, 64);
        ss += __shfl_xor(ss, off, 64);
    }
    float mu  = s * (1.0f / D);
    float var = ss * (1.0f / D) - mu * mu;
    float rs  = rsqrtf(var + EPS);
    float* y = hn + (long long)row * D;
    y[lane]      = (a - mu) * rs * gamma[lane]      + beta[lane];
    y[lane + 64] = (c - mu) * rs * gamma[lane + 64] + beta[lane + 64];
}

// ---------------------------------------------------------------------------
// W [128][256] -> Wt [256][128]  (tiny, once per call)
// ---------------------------------------------------------------------------
__global__ __launch_bounds__(256) void transpose_W(const float* __restrict__ W,
                                                   float* __restrict__ Wt) {
    int idx = blockIdx.x * blockDim.x + threadIdx.x;
    if (idx < 128 * 256) {
        int j = idx >> 8;     // output feature
        int k = idx & 255;    // input feature
        Wt[k * 128 + j] = W[idx];
    }
}

// ---------------------------------------------------------------------------
// edge scatter: 32 threads/edge, float4 gather + 4 f32 atomics
// ---------------------------------------------------------------------------
__global__ __launch_bounds__(256) void scatter_kernel(const void* edges,
                                                      const float* __restrict__ hn,
                                                      const float* __restrict__ inv_out,
                                                      float* agg,
                                                      const int* flag) {
    int is64 = *flag;
    long long gid = (long long)blockIdx.x * blockDim.x + threadIdx.x;
    long long e = gid >> 5;
    if (e >= N_EDGES) return;
    int c = (int)(gid & 31) * 4;
    int s = load_idx(edges, e, is64);
    int d = load_idx(edges, (long long)N_EDGES + e, is64);
    float sc = inv_out[s];
    const float4 v = *(const float4*)(hn + (long long)s * D + c);
    float* dst = agg + (long long)d * D + c;
    atomicAdd(dst + 0, v.x * sc);
    atomicAdd(dst + 1, v.y * sc);
    atomicAdd(dst + 2, v.z * sc);
    atomicAdd(dst + 3, v.w * sc);
}

// ---------------------------------------------------------------------------
// output: out[n][j] = b[j] + sum_k cat[n][k] * Wt[k][j]
// block = 128 threads (thread j = out feature), 16 rows per block
// ---------------------------------------------------------------------------
__global__ __launch_bounds__(128) void out_kernel(const float* __restrict__ hn,
                                                  const float* __restrict__ agg,
                                                  const float* __restrict__ inv_in,
                                                  const float* __restrict__ Wt,
                                                  const float* __restrict__ bias,
                                                  float* __restrict__ out) {
    __shared__ float cat[16][256];
    int t = threadIdx.x;
    int base = blockIdx.x * 16;
    for (int r = 0; r < 16; ++r) {
        int n = base + r;
        float ii = inv_in[n];
        cat[r][t]       = hn[(long long)n * D + t];
        cat[r][128 + t] = agg[(long long)n * D + t] * ii;
    }
    __syncthreads();
    float acc[16];
    #pragma unroll
    for (int r = 0; r < 16; ++r) acc[r] = 0.0f;
    for (int k = 0; k < 256; ++k) {
        float w = Wt[k * 128 + t];
        #pragma unroll
        for (int r = 0; r < 16; ++r) acc[r] += cat[r][k] * w;
    }
    float bb = bias[t];
    #pragma unroll
    for (int r = 0; r < 16; ++r)
        out[(long long)(base + r) * D + t] = acc[r] + bb;
}

// ---------------------------------------------------------------------------
extern "C" void kernel_launch(void* const* d_in, const int* in_sizes, int n_in,
                              void* d_out, int out_size, void* d_ws, size_t ws_size,
                              hipStream_t stream) {
    const float* h     = (const float*)d_in[0];
    const void*  edges = d_in[1];
    const float* gamma = (const float*)d_in[2];
    const float* beta  = (const float*)d_in[3];
    const float* W     = (const float*)d_in[4];
    const float* bias  = (const float*)d_in[5];
    float* out = (float*)d_out;

    // workspace layout (bytes)
    char* ws = (char*)d_ws;
    const size_t agg_off   = 0;                              // N*D*4 = 25,600,000
    const size_t dego_off  = agg_off  + (size_t)N_NODES * D * 4;   // 200,000
    const size_t degi_off  = dego_off + (size_t)N_NODES * 4;       // 200,000
    const size_t flag_off  = degi_off + (size_t)N_NODES * 4;       // 16
    const size_t wt_off    = flag_off + 16;                        // 131,072
    const size_t hn_off    = wt_off   + (size_t)128 * 256 * 4;     // 25,600,000

    float*        agg     = (float*)(ws + agg_off);
    unsigned int* deg_out = (unsigned int*)(ws + dego_off);
    unsigned int* deg_in  = (unsigned int*)(ws + degi_off);
    int*          flag    = (int*)(ws + flag_off);
    float*        Wt      = (float*)(ws + wt_off);
    float*        hn      = (float*)(ws + hn_off);

    // zero agg + both degree arrays in one shot
    hipMemsetAsync(ws, 0, (size_t)N_NODES * D * 4 + 2 * (size_t)N_NODES * 4, stream);

    detect_idx64<<<1, 64, 0, stream>>>((const unsigned int*)edges, flag);

    deg_kernel<<<(N_EDGES + 255) / 256, 256, 0, stream>>>(edges, deg_out, deg_in, flag);
    inv_sqrt_kernel<<<(N_NODES + 255) / 256, 256, 0, stream>>>(deg_out, deg_in);

    ln_kernel<<<(N_NODES + 3) / 4, 256, 0, stream>>>(h, gamma, beta, hn);
    transpose_W<<<(128 * 256 + 255) / 256, 256, 0, stream>>>(W, Wt);

    long long scatter_threads = (long long)N_EDGES * 32;
    scatter_kernel<<<(unsigned)((scatter_threads + 255) / 256), 256, 0, stream>>>(
        edges, hn, (const float*)deg_out, agg, flag);

    out_kernel<<<N_NODES / 16, 128, 0, stream>>>(hn, agg, (const float*)deg_in, Wt, bias, out);
}

// Round 2
// 400.858 us; speedup vs baseline: 2.9194x; 2.9194x over previous
//
#include <hip/hip_runtime.h>
#include <stdint.h>

#define N_NODES 50000
#define N_EDGES 600000
#define D       128
#define EPS     1e-5f

// ---------------------------------------------------------------------------
// edge dtype detection: int64 vs int32 (see round-0 note)
// ---------------------------------------------------------------------------
__global__ void detect_idx64(const unsigned int* e, int* flag) {
    if (blockIdx.x == 0 && threadIdx.x == 0) {
        int is64 = 1;
        for (int i = 0; i < 128; ++i)
            if (e[2 * i + 1] != 0u) { is64 = 0; break; }
        *flag = is64;
    }
}

__device__ __forceinline__ int load_idx(const void* e, long long i, int is64) {
    return is64 ? (int)((const long long*)e)[i] : ((const int*)e)[i];
}

// ---------------------------------------------------------------------------
// degree counting (u32 atomics, raw counts)
// ---------------------------------------------------------------------------
__global__ __launch_bounds__(256) void deg_kernel(const void* edges,
                                                  unsigned int* deg_out,
                                                  unsigned int* deg_in,
                                                  const int* flag) {
    int is64 = *flag;
    int i = blockIdx.x * blockDim.x + threadIdx.x;
    if (i < N_EDGES) {
        int s = load_idx(edges, i, is64);
        int d = load_idx(edges, (long long)N_EDGES + i, is64);
        atomicAdd(&deg_out[s], 1u);
        atomicAdd(&deg_in[d], 1u);
    }
}

// u32 degree -> f32 rsqrt(max(deg,1)) into separate arrays
__global__ __launch_bounds__(256) void inv_sqrt_kernel(const unsigned int* deg_out,
                                                       const unsigned int* deg_in,
                                                       float* inv_out,
                                                       float* inv_in) {
    int i = blockIdx.x * blockDim.x + threadIdx.x;
    if (i < N_NODES) {
        float o = (float)(deg_out[i] > 1u ? deg_out[i] : 1u);
        float g = (float)(deg_in[i]  > 1u ? deg_in[i]  : 1u);
        inv_out[i] = rsqrtf(o);
        inv_in[i]  = rsqrtf(g);
    }
}

// ---------------------------------------------------------------------------
// exclusive scan of deg_in -> row_start[N+1], cursor[N] (single 1024-thread block)
// ---------------------------------------------------------------------------
__global__ __launch_bounds__(1024) void scan_kernel(const unsigned int* __restrict__ deg,
                                                    unsigned int* __restrict__ row_start,
                                                    unsigned int* __restrict__ cursor) {
    __shared__ unsigned int buf[1024];
    const int CHUNK = (N_NODES + 1023) / 1024;  // 49
    int t = threadIdx.x;
    int lo = t * CHUNK;
    int hi = lo + CHUNK; if (hi > N_NODES) hi = N_NODES;
    unsigned int s = 0;
    for (int i = lo; i < hi; ++i) s += deg[i];
    buf[t] = s;
    __syncthreads();
    // Hillis-Steele inclusive scan
    for (int off = 1; off < 1024; off <<= 1) {
        unsigned int v = (t >= off) ? buf[t - off] : 0u;
        __syncthreads();
        buf[t] += v;
        __syncthreads();
    }
    unsigned int run = buf[t] - s;  // exclusive prefix of this thread's chunk
    for (int i = lo; i < hi; ++i) {
        row_start[i] = run;
        cursor[i]    = run;
        run += deg[i];
    }
    if (t == 1023) row_start[N_NODES] = N_EDGES;
}

// ---------------------------------------------------------------------------
// bucket fill: csr_src[pos] = src for each edge, bucketed by dst
// ---------------------------------------------------------------------------
__global__ __launch_bounds__(256) void fill_csr(const void* edges,
                                                unsigned int* cursor,
                                                unsigned int* csr_src,
                                                const int* flag) {
    int is64 = *flag;
    int i = blockIdx.x * blockDim.x + threadIdx.x;
    if (i < N_EDGES) {
        int s = load_idx(edges, i, is64);
        int d = load_idx(edges, (long long)N_EDGES + i, is64);
        unsigned int pos = atomicAdd(&cursor[d], 1u);
        csr_src[pos] = (unsigned int)s;
    }
}

// ---------------------------------------------------------------------------
// LayerNorm: one wave per row, 2 elems/lane
// ---------------------------------------------------------------------------
__global__ __launch_bounds__(256) void ln_kernel(const float* __restrict__ h,
                                                 const float* __restrict__ gamma,
                                                 const float* __restrict__ beta,
                                                 float* __restrict__ hn) {
    int wid  = threadIdx.x >> 6;
    int lane = threadIdx.x & 63;
    int row  = blockIdx.x * 4 + wid;
    if (row >= N_NODES) return;
    const float* x = h + (long long)row * D;
    float a = x[lane];
    float c = x[lane + 64];
    float s  = a + c;
    float ss = a * a + c * c;
    #pragma unroll
    for (int off = 32; off; off >>= 1) {
        s  += __shfl_xor(s,  off, 64);
        ss += __shfl_xor(ss, off, 64);
    }
    float mu  = s * (1.0f / D);
    float var = ss * (1.0f / D) - mu * mu;
    float rs  = rsqrtf(var + EPS);
    float* y = hn + (long long)row * D;
    y[lane]      = (a - mu) * rs * gamma[lane]      + beta[lane];
    y[lane + 64] = (c - mu) * rs * gamma[lane + 64] + beta[lane + 64];
}

// ---------------------------------------------------------------------------
// W [128][256] -> Wt [256][128]
// ---------------------------------------------------------------------------
__global__ __launch_bounds__(256) void transpose_W(const float* __restrict__ W,
                                                   float* __restrict__ Wt) {
    int idx = blockIdx.x * blockDim.x + threadIdx.x;
    if (idx < 128 * 256) {
        int j = idx >> 8;
        int k = idx & 255;
        Wt[k * 128 + j] = W[idx];
    }
}

// ---------------------------------------------------------------------------
// fused: CSR pull-aggregation into LDS + [16,256]x[256,128] GEMM
// block = 128 threads (thread t = out feature), 16 rows per block
// ---------------------------------------------------------------------------
__global__ __launch_bounds__(128) void out_kernel(const float* __restrict__ hn,
                                                  const float* __restrict__ inv_out,
                                                  const float* __restrict__ inv_in,
                                                  const unsigned int* __restrict__ row_start,
                                                  const unsigned int* __restrict__ csr_src,
                                                  const float* __restrict__ Wt,
                                                  const float* __restrict__ bias,
                                                  float* __restrict__ out) {
    __shared__ float cat[16][256];
    int t = threadIdx.x;
    int base = blockIdx.x * 16;

    for (int r = 0; r < 16; ++r) {
        int n = base + r;
        cat[r][t] = hn[(long long)n * D + t];
        float acc = 0.0f;
        unsigned int e0 = row_start[n], e1 = row_start[n + 1];
        for (unsigned int e = e0; e < e1; ++e) {
            int src = (int)csr_src[e];
            acc += hn[(long long)src * D + t] * inv_out[src];
        }
        cat[r][128 + t] = acc * inv_in[n];
    }
    __syncthreads();

    float acc[16];
    #pragma unroll
    for (int r = 0; r < 16; ++r) acc[r] = 0.0f;
    for (int k = 0; k < 256; ++k) {
        float w = Wt[k * 128 + t];
        #pragma unroll
        for (int r = 0; r < 16; ++r) acc[r] += cat[r][k] * w;
    }
    float bb = bias[t];
    #pragma unroll
    for (int r = 0; r < 16; ++r)
        out[(long long)(base + r) * D + t] = acc[r] + bb;
}

// ---------------------------------------------------------------------------
extern "C" void kernel_launch(void* const* d_in, const int* in_sizes, int n_in,
                              void* d_out, int out_size, void* d_ws, size_t ws_size,
                              hipStream_t stream) {
    const float* h     = (const float*)d_in[0];
    const void*  edges = d_in[1];
    const float* gamma = (const float*)d_in[2];
    const float* beta  = (const float*)d_in[3];
    const float* W     = (const float*)d_in[4];
    const float* bias  = (const float*)d_in[5];
    float* out = (float*)d_out;

    // workspace layout (bytes), all 256-aligned
    char* ws = (char*)d_ws;
    size_t off = 0;
    auto alloc = [&](size_t bytes) { size_t o = off; off += (bytes + 255) & ~(size_t)255; return o; };
    unsigned int* deg_out  = (unsigned int*)(ws + alloc((size_t)N_NODES * 4));
    unsigned int* deg_in   = (unsigned int*)(ws + alloc((size_t)N_NODES * 4));
    float*        inv_out  = (float*)(ws + alloc((size_t)N_NODES * 4));
    float*        inv_in   = (float*)(ws + alloc((size_t)N_NODES * 4));
    unsigned int* row_start= (unsigned int*)(ws + alloc((size_t)(N_NODES + 1) * 4));
    unsigned int* cursor   = (unsigned int*)(ws + alloc((size_t)N_NODES * 4));
    int*          flag     = (int*)(ws + alloc(16));
    float*        Wt       = (float*)(ws + alloc((size_t)256 * 128 * 4));
    unsigned int* csr_src  = (unsigned int*)(ws + alloc((size_t)N_EDGES * 4));
    float*        hn       = (float*)(ws + alloc((size_t)N_NODES * D * 4));

    // zero the two degree arrays (they are at offsets 0 and N*4, contiguous)
    hipMemsetAsync(ws, 0, 2 * ((size_t)N_NODES * 4 + 255 & ~(size_t)255), stream);

    detect_idx64<<<1, 64, 0, stream>>>((const unsigned int*)edges, flag);
    deg_kernel<<<(N_EDGES + 255) / 256, 256, 0, stream>>>(edges, deg_out, deg_in, flag);
    inv_sqrt_kernel<<<(N_NODES + 255) / 256, 256, 0, stream>>>(deg_out, deg_in, inv_out, inv_in);
    scan_kernel<<<1, 1024, 0, stream>>>(deg_in, row_start, cursor);
    ln_kernel<<<(N_NODES + 3) / 4, 256, 0, stream>>>(h, gamma, beta, hn);
    transpose_W<<<(128 * 256 + 255) / 256, 256, 0, stream>>>(W, Wt);
    fill_csr<<<(N_EDGES + 255) / 256, 256, 0, stream>>>(edges, cursor, csr_src, flag);
    out_kernel<<<N_NODES / 16, 128, 0, stream>>>(hn, inv_out, inv_in, row_start, csr_src,
                                                 Wt, bias, out);
}

// Round 3
// 286.724 us; speedup vs baseline: 4.0815x; 1.3981x over previous
//
#include <hip/hip_runtime.h>
#include <stdint.h>

#define N_NODES 50000
#define N_EDGES 600000
#define D       128
#define EPS     1e-5f

// ---------------------------------------------------------------------------
// edge dtype detection (int64 vs int32), 64-lane ballot version.
// int64: high word of every value < 50000 is 0. int32: P(64 odd samples
// all zero) = (1/50000)^64 ~ 0.
// ---------------------------------------------------------------------------
__global__ void detect_idx64(const unsigned int* e, int* flag) {
    int lane = threadIdx.x & 63;
    unsigned int v = e[2 * lane + 1];
    unsigned long long nz = __ballot(v != 0u);
    if (threadIdx.x == 0) *flag = (nz == 0ull) ? 1 : 0;
}

__device__ __forceinline__ int load_idx(const void* e, long long i, int is64) {
    return is64 ? (int)((const long long*)e)[i] : ((const int*)e)[i];
}

// ---------------------------------------------------------------------------
// degree counting (u32 atomics)
// ---------------------------------------------------------------------------
__global__ __launch_bounds__(256) void deg_kernel(const void* edges,
                                                  unsigned int* deg_out,
                                                  unsigned int* deg_in,
                                                  const int* flag) {
    int is64 = *flag;
    int i = blockIdx.x * blockDim.x + threadIdx.x;
    if (i < N_EDGES) {
        int s = load_idx(edges, i, is64);
        int d = load_idx(edges, (long long)N_EDGES + i, is64);
        atomicAdd(&deg_out[s], 1u);
        atomicAdd(&deg_in[d], 1u);
    }
}

__global__ __launch_bounds__(256) void inv_sqrt_kernel(const unsigned int* deg_out,
                                                       const unsigned int* deg_in,
                                                       float* inv_out,
                                                       float* inv_in) {
    int i = blockIdx.x * blockDim.x + threadIdx.x;
    if (i < N_NODES) {
        float o = (float)(deg_out[i] > 1u ? deg_out[i] : 1u);
        float g = (float)(deg_in[i]  > 1u ? deg_in[i]  : 1u);
        inv_out[i] = rsqrtf(o);
        inv_in[i]  = rsqrtf(g);
    }
}

// ---------------------------------------------------------------------------
// exclusive scan of deg_in -> row_start[N+1], cursor[N]
// single 1024-thread block, coalesced tiles of 1024, wave shfl-scan
// ---------------------------------------------------------------------------
__global__ __launch_bounds__(1024) void scan_kernel(const unsigned int* __restrict__ deg,
                                                    unsigned int* __restrict__ row_start,
                                                    unsigned int* __restrict__ cursor) {
    __shared__ unsigned int wsum[16];
    int t = threadIdx.x;
    int lane = t & 63;
    int w = t >> 6;
    unsigned int carry = 0;
    for (int base = 0; base < N_NODES; base += 1024) {
        int i = base + t;
        unsigned int v = (i < N_NODES) ? deg[i] : 0u;
        // wave inclusive scan
        unsigned int x = v;
        #pragma unroll
        for (int off = 1; off < 64; off <<= 1) {
            unsigned int y = __shfl_up(x, off, 64);
            if (lane >= off) x += y;
        }
        if (lane == 63) wsum[w] = x;
        __syncthreads();
        if (w == 0) {
            unsigned int s = (lane < 16) ? wsum[lane] : 0u;
            #pragma unroll
            for (int off = 1; off < 16; off <<= 1) {
                unsigned int y = __shfl_up(s, off, 64);
                if (lane >= off) s += y;
            }
            if (lane < 16) wsum[lane] = s;
        }
        __syncthreads();
        unsigned int woff = (w == 0) ? 0u : wsum[w - 1];
        unsigned int excl = carry + woff + x - v;
        if (i < N_NODES) { row_start[i] = excl; cursor[i] = excl; }
        carry += wsum[15];
        __syncthreads();
    }
    if (t == 0) row_start[N_NODES] = N_EDGES;
}

// ---------------------------------------------------------------------------
// bucket fill: csr_src[pos] = src for each edge, bucketed by dst
// ---------------------------------------------------------------------------
__global__ __launch_bounds__(256) void fill_csr(const void* edges,
                                                unsigned int* cursor,
                                                unsigned int* csr_src,
                                                const int* flag) {
    int is64 = *flag;
    int i = blockIdx.x * blockDim.x + threadIdx.x;
    if (i < N_EDGES) {
        int s = load_idx(edges, i, is64);
        int d = load_idx(edges, (long long)N_EDGES + i, is64);
        unsigned int pos = atomicAdd(&cursor[d], 1u);
        csr_src[pos] = (unsigned int)s;
    }
}

// ---------------------------------------------------------------------------
// LayerNorm: one wave per row, 2 elems/lane
// ---------------------------------------------------------------------------
__global__ __launch_bounds__(256) void ln_kernel(const float* __restrict__ h,
                                                 const float* __restrict__ gamma,
                                                 const float* __restrict__ beta,
                                                 float* __restrict__ hn) {
    int wid  = threadIdx.x >> 6;
    int lane = threadIdx.x & 63;
    int row  = blockIdx.x * 4 + wid;
    if (row >= N_NODES) return;
    const float* x = h + (long long)row * D;
    float a = x[lane];
    float c = x[lane + 64];
    float s  = a + c;
    float ss = a * a + c * c;
    #pragma unroll
    for (int off = 32; off; off >>= 1) {
        s  += __shfl_xor(s,  off, 64);
        ss += __shfl_xor(ss, off, 64);
    }
    float mu  = s * (1.0f / D);
    float var = ss * (1.0f / D) - mu * mu;
    float rs  = rsqrtf(var + EPS);
    float* y = hn + (long long)row * D;
    y[lane]      = (a - mu) * rs * gamma[lane]      + beta[lane];
    y[lane + 64] = (c - mu) * rs * gamma[lane + 64] + beta[lane + 64];
}

// ---------------------------------------------------------------------------
// W [128][256] -> Wt [256][128]
// ---------------------------------------------------------------------------
__global__ __launch_bounds__(256) void transpose_W(const float* __restrict__ W,
                                                   float* __restrict__ Wt) {
    int idx = blockIdx.x * blockDim.x + threadIdx.x;
    if (idx < 128 * 256) {
        int j = idx >> 8;
        int k = idx & 255;
        Wt[k * 128 + j] = W[idx];
    }
}

// ---------------------------------------------------------------------------
// aggregation: one wave per dst row, lane = 2 features (float2)
// csr_src pre-loaded 64-wide coalesced, shfl-broadcast per edge
// ---------------------------------------------------------------------------
__global__ __launch_bounds__(256) void agg_kernel(const float* __restrict__ hn,
                                                  const float* __restrict__ inv_out,
                                                  const float* __restrict__ inv_in,
                                                  const unsigned int* __restrict__ row_start,
                                                  const unsigned int* __restrict__ csr_src,
                                                  float* __restrict__ agg) {
    int wid  = threadIdx.x >> 6;
    int lane = threadIdx.x & 63;
    int row  = blockIdx.x * 4 + wid;
    if (row >= N_NODES) return;
    const float2* hn2 = (const float2*)hn;
    unsigned int e0 = row_start[row], e1 = row_start[row + 1];
    float ax = 0.0f, ay = 0.0f;
    unsigned int e = e0;
    while (e < e1) {
        unsigned int cnt = e1 - e;
        if (cnt > 64u) cnt = 64u;
        int sl = (lane < (int)cnt) ? (int)csr_src[e + lane] : 0;
        for (int i = 0; i < (int)cnt; ++i) {
            int s = __shfl(sl, i, 64);
            float sc = inv_out[s];
            float2 v = hn2[(long long)s * 64 + lane];
            ax = fmaf(v.x, sc, ax);
            ay = fmaf(v.y, sc, ay);
        }
        e += cnt;
    }
    float ii = inv_in[row];
    ((float2*)agg)[(long long)row * 64 + lane] = make_float2(ax * ii, ay * ii);
}

// ---------------------------------------------------------------------------
// GEMM: out[n][t] = b[t] + sum_k cat[n][k] * Wt[k][t]
// cat = [hn | agg] staged in LDS; 16 rows per 128-thread block; k unroll x4
// ---------------------------------------------------------------------------
__global__ __launch_bounds__(128) void gemm_kernel(const float* __restrict__ hn,
                                                   const float* __restrict__ agg,
                                                   const float* __restrict__ Wt,
                                                   const float* __restrict__ bias,
                                                   float* __restrict__ out) {
    __shared__ float cat[16][256];
    int t = threadIdx.x;
    int base = blockIdx.x * 16;
    for (int r = 0; r < 16; ++r) {
        int n = base + r;
        cat[r][t]       = hn[(long long)n * D + t];
        cat[r][128 + t] = agg[(long long)n * D + t];
    }
    __syncthreads();

    float acc[16];
    #pragma unroll
    for (int r = 0; r < 16; ++r) acc[r] = 0.0f;

    const float4 (*cat4)[64] = (const float4 (*)[64])cat;
    for (int k4 = 0; k4 < 64; ++k4) {
        float w0 = Wt[(k4 * 4 + 0) * 128 + t];
        float w1 = Wt[(k4 * 4 + 1) * 128 + t];
        float w2 = Wt[(k4 * 4 + 2) * 128 + t];
        float w3 = Wt[(k4 * 4 + 3) * 128 + t];
        #pragma unroll
        for (int r = 0; r < 16; ++r) {
            float4 c = cat4[r][k4];
            acc[r] += c.x * w0 + c.y * w1 + c.z * w2 + c.w * w3;
        }
    }
    float bb = bias[t];
    #pragma unroll
    for (int r = 0; r < 16; ++r)
        out[(long long)(base + r) * D + t] = acc[r] + bb;
}

// ---------------------------------------------------------------------------
extern "C" void kernel_launch(void* const* d_in, const int* in_sizes, int n_in,
                              void* d_out, int out_size, void* d_ws, size_t ws_size,
                              hipStream_t stream) {
    const float* h     = (const float*)d_in[0];
    const void*  edges = d_in[1];
    const float* gamma = (const float*)d_in[2];
    const float* beta  = (const float*)d_in[3];
    const float* W     = (const float*)d_in[4];
    const float* bias  = (const float*)d_in[5];
    float* out = (float*)d_out;

    char* ws = (char*)d_ws;
    size_t off = 0;
    auto alloc = [&](size_t bytes) { size_t o = off; off += (bytes + 255) & ~(size_t)255; return o; };
    unsigned int* deg_out   = (unsigned int*)(ws + alloc((size_t)N_NODES * 4));
    unsigned int* deg_in    = (unsigned int*)(ws + alloc((size_t)N_NODES * 4));
    float*        inv_out   = (float*)(ws + alloc((size_t)N_NODES * 4));
    float*        inv_in    = (float*)(ws + alloc((size_t)N_NODES * 4));
    unsigned int* row_start = (unsigned int*)(ws + alloc((size_t)(N_NODES + 1) * 4));
    unsigned int* cursor    = (unsigned int*)(ws + alloc((size_t)N_NODES * 4));
    int*          flag      = (int*)(ws + alloc(16));
    float*        Wt        = (float*)(ws + alloc((size_t)256 * 128 * 4));
    unsigned int* csr_src   = (unsigned int*)(ws + alloc((size_t)N_EDGES * 4));
    float*        agg       = (float*)(ws + alloc((size_t)N_NODES * D * 4));
    float*        hn        = (float*)(ws + alloc((size_t)N_NODES * D * 4));

    // zero deg_out + deg_in (first two 256-aligned regions, contiguous)
    size_t degpad = ((size_t)N_NODES * 4 + 255) & ~(size_t)255;
    hipMemsetAsync(ws, 0, 2 * degpad, stream);

    detect_idx64<<<1, 64, 0, stream>>>((const unsigned int*)edges, flag);
    deg_kernel<<<(N_EDGES + 255) / 256, 256, 0, stream>>>(edges, deg_out, deg_in, flag);
    inv_sqrt_kernel<<<(N_NODES + 255) / 256, 256, 0, stream>>>(deg_out, deg_in, inv_out, inv_in);
    scan_kernel<<<1, 1024, 0, stream>>>(deg_in, row_start, cursor);
    ln_kernel<<<(N_NODES + 3) / 4, 256, 0, stream>>>(h, gamma, beta, hn);
    transpose_W<<<(128 * 256 + 255) / 256, 256, 0, stream>>>(W, Wt);
    fill_csr<<<(N_EDGES + 255) / 256, 256, 0, stream>>>(edges, cursor, csr_src, flag);
    agg_kernel<<<(N_NODES + 3) / 4, 256, 0, stream>>>(hn, inv_out, inv_in, row_start,
                                                      csr_src, agg);
    gemm_kernel<<<N_NODES / 16, 128, 0, stream>>>(hn, agg, Wt, bias, out);
}

// Round 4
// 172.406 us; speedup vs baseline: 6.7878x; 1.6631x over previous
//
#include <hip/hip_runtime.h>
#include <stdint.h>

#define N_NODES 50000
#define N_EDGES 600000
#define D       128
#define EPS     1e-5f

typedef __attribute__((ext_vector_type(8))) short bf16x8;   // 8 bf16 = 4 VGPR
typedef __attribute__((ext_vector_type(4))) float f32x4;    // MFMA acc

__device__ __forceinline__ unsigned short f2bf(float x) {   // RNE f32->bf16
    unsigned int u = __float_as_uint(x);
    return (unsigned short)((u + 0x7fffu + ((u >> 16) & 1u)) >> 16);
}

// ---------------------------------------------------------------------------
// edge dtype detection (int64 vs int32), 64-lane ballot
// ---------------------------------------------------------------------------
__global__ void detect_idx64(const unsigned int* e, int* flag) {
    int lane = threadIdx.x & 63;
    unsigned int v = e[2 * lane + 1];
    unsigned long long nz = __ballot(v != 0u);
    if (threadIdx.x == 0) *flag = (nz == 0ull) ? 1 : 0;
}

__device__ __forceinline__ int load_idx(const void* e, long long i, int is64) {
    return is64 ? (int)((const long long*)e)[i] : ((const int*)e)[i];
}

// ---------------------------------------------------------------------------
// degree counting
// ---------------------------------------------------------------------------
__global__ __launch_bounds__(256) void deg_kernel(const void* edges,
                                                  unsigned int* deg_out,
                                                  unsigned int* deg_in,
                                                  const int* flag) {
    int is64 = *flag;
    int i = blockIdx.x * blockDim.x + threadIdx.x;
    if (i < N_EDGES) {
        int s = load_idx(edges, i, is64);
        int d = load_idx(edges, (long long)N_EDGES + i, is64);
        atomicAdd(&deg_out[s], 1u);
        atomicAdd(&deg_in[d], 1u);
    }
}

__global__ __launch_bounds__(256) void inv_sqrt_kernel(const unsigned int* deg_out,
                                                       const unsigned int* deg_in,
                                                       float* inv_out,
                                                       float* inv_in) {
    int i = blockIdx.x * blockDim.x + threadIdx.x;
    if (i < N_NODES) {
        float o = (float)(deg_out[i] > 1u ? deg_out[i] : 1u);
        float g = (float)(deg_in[i]  > 1u ? deg_in[i]  : 1u);
        inv_out[i] = rsqrtf(o);
        inv_in[i]  = rsqrtf(g);
    }
}

// ---------------------------------------------------------------------------
// two-phase multi-block exclusive scan of deg_in (49 blocks x 1024)
// ---------------------------------------------------------------------------
__global__ __launch_bounds__(1024) void scan1(const unsigned int* __restrict__ deg,
                                              unsigned int* __restrict__ row_start,
                                              unsigned int* __restrict__ partials) {
    __shared__ unsigned int wsum[16];
    int t = threadIdx.x, lane = t & 63, w = t >> 6;
    int i = blockIdx.x * 1024 + t;
    unsigned int v = (i < N_NODES) ? deg[i] : 0u;
    unsigned int x = v;
    #pragma unroll
    for (int off = 1; off < 64; off <<= 1) {
        unsigned int y = __shfl_up(x, off, 64);
        if (lane >= off) x += y;
    }
    if (lane == 63) wsum[w] = x;
    __syncthreads();
    if (w == 0) {
        unsigned int s = (lane < 16) ? wsum[lane] : 0u;
        #pragma unroll
        for (int off = 1; off < 16; off <<= 1) {
            unsigned int y = __shfl_up(s, off, 64);
            if (lane >= off) s += y;
        }
        if (lane < 16) wsum[lane] = s;
    }
    __syncthreads();
    unsigned int excl = (w ? wsum[w - 1] : 0u) + x - v;
    if (i < N_NODES) row_start[i] = excl;
    if (t == 1023) partials[blockIdx.x] = wsum[15];
}

__global__ __launch_bounds__(1024) void scan2(const unsigned int* __restrict__ partials,
                                              unsigned int* __restrict__ row_start,
                                              unsigned int* __restrict__ cursor) {
    __shared__ unsigned int soff;
    int t = threadIdx.x, b = blockIdx.x;
    if (t < 64) {
        unsigned int p = (t < b) ? partials[t] : 0u;   // b <= 48 < 64
        #pragma unroll
        for (int off = 32; off; off >>= 1) p += __shfl_xor(p, off, 64);
        if (t == 0) soff = p;
    }
    __syncthreads();
    int i = b * 1024 + t;
    if (i < N_NODES) {
        unsigned int r = row_start[i] + soff;
        row_start[i] = r;
        cursor[i]    = r;
    }
    if (b == 0 && t == 0) row_start[N_NODES] = N_EDGES;
}

// ---------------------------------------------------------------------------
// bucket fill: csr_src[pos] = src, bucketed by dst
// ---------------------------------------------------------------------------
__global__ __launch_bounds__(256) void fill_csr(const void* edges,
                                                unsigned int* cursor,
                                                unsigned int* csr_src,
                                                const int* flag) {
    int is64 = *flag;
    int i = blockIdx.x * blockDim.x + threadIdx.x;
    if (i < N_EDGES) {
        int s = load_idx(edges, i, is64);
        int d = load_idx(edges, (long long)N_EDGES + i, is64);
        unsigned int pos = atomicAdd(&cursor[d], 1u);
        csr_src[pos] = (unsigned int)s;
    }
}

// ---------------------------------------------------------------------------
// LayerNorm -> bf16 output (packed pairs). lane owns features 2l, 2l+1.
// ---------------------------------------------------------------------------
__global__ __launch_bounds__(256) void ln_kernel(const float2* __restrict__ h2,
                                                 const float2* __restrict__ g2,
                                                 const float2* __restrict__ b2,
                                                 unsigned int* __restrict__ hnb) {
    int wid  = threadIdx.x >> 6;
    int lane = threadIdx.x & 63;
    int row  = blockIdx.x * 4 + wid;
    if (row >= N_NODES) return;
    float2 v = h2[(size_t)row * 64 + lane];
    float s  = v.x + v.y;
    float ss = v.x * v.x + v.y * v.y;
    #pragma unroll
    for (int off = 32; off; off >>= 1) {
        s  += __shfl_xor(s,  off, 64);
        ss += __shfl_xor(ss, off, 64);
    }
    float mu  = s * (1.0f / D);
    float var = ss * (1.0f / D) - mu * mu;
    float rs  = rsqrtf(var + EPS);
    float2 g = g2[lane], b = b2[lane];
    float y0 = (v.x - mu) * rs * g.x + b.x;
    float y1 = (v.y - mu) * rs * g.y + b.y;
    hnb[(size_t)row * 64 + lane] = (unsigned int)f2bf(y0) | ((unsigned int)f2bf(y1) << 16);
}

// ---------------------------------------------------------------------------
// W f32 [128][256] -> bf16 packed (same layout)
// ---------------------------------------------------------------------------
__global__ __launch_bounds__(256) void cast_W(const float2* __restrict__ W2,
                                              unsigned int* __restrict__ Wb) {
    int i = blockIdx.x * 256 + threadIdx.x;
    if (i < 128 * 128) {
        float2 w = W2[i];
        Wb[i] = (unsigned int)f2bf(w.x) | ((unsigned int)f2bf(w.y) << 16);
    }
}

// ---------------------------------------------------------------------------
// aggregation: one wave per dst row; lane = packed bf16 feature pair (4 B)
// ---------------------------------------------------------------------------
__global__ __launch_bounds__(256) void agg_kernel(const unsigned int* __restrict__ hnb,
                                                  const float* __restrict__ inv_out,
                                                  const float* __restrict__ inv_in,
                                                  const unsigned int* __restrict__ row_start,
                                                  const unsigned int* __restrict__ csr_src,
                                                  unsigned int* __restrict__ aggb) {
    int wid  = threadIdx.x >> 6;
    int lane = threadIdx.x & 63;
    int row  = blockIdx.x * 4 + wid;
    if (row >= N_NODES) return;
    unsigned int e0 = row_start[row], e1 = row_start[row + 1];
    float ax = 0.0f, ay = 0.0f;
    unsigned int e = e0;
    while (e < e1) {
        unsigned int cnt = e1 - e;
        if (cnt > 64u) cnt = 64u;
        int sl = (lane < (int)cnt) ? (int)csr_src[e + lane] : 0;
        for (int i = 0; i < (int)cnt; ++i) {
            int s = __shfl(sl, i, 64);
            float sc = inv_out[s];
            unsigned int v = hnb[(size_t)s * 64 + lane];
            ax = fmaf(__uint_as_float(v << 16), sc, ax);
            ay = fmaf(__uint_as_float(v & 0xffff0000u), sc, ay);
        }
        e += cnt;
    }
    float ii = inv_in[row];
    aggb[(size_t)row * 64 + lane] =
        (unsigned int)f2bf(ax * ii) | ((unsigned int)f2bf(ay * ii) << 16);
}

// ---------------------------------------------------------------------------
// MFMA GEMM: out[50000][128] = cat([hn|agg]) @ W^T + b
// block = 256 thr (4 waves), 64 rows x 128 cols per block.
// W (bf16, [128 out][256 k]) staged in LDS, +8 elem row pad (stride 528 B).
// A-frags straight from global bf16: lane=(lrow,lhi), row=rbase+lrow,
// k = kc*32 + lhi*8 .. +8 (16 B per lane).
// ---------------------------------------------------------------------------
__global__ __launch_bounds__(256) void gemm_kernel(const unsigned short* __restrict__ hnb,
                                                   const unsigned short* __restrict__ aggb,
                                                   const unsigned short* __restrict__ Wb,
                                                   const float* __restrict__ bias,
                                                   float* __restrict__ out) {
    __shared__ unsigned short wlds[128 * 264];
    int t = threadIdx.x;
    // stage W: thread t loads row j=t>>1, half=t&1 (128 elems = 16 uint4)
    {
        int j = t >> 1, half = t & 1;
        const uint4* src = (const uint4*)(Wb + (size_t)j * 256 + half * 128);
        uint4* dst = (uint4*)(wlds + j * 264 + half * 128);
        #pragma unroll
        for (int i = 0; i < 16; ++i) dst[i] = src[i];
    }
    __syncthreads();

    int w = t >> 6, lane = t & 63;
    int rbase = blockIdx.x * 64 + w * 16;
    if (rbase >= N_NODES) return;
    int lrow = lane & 15, lhi = lane >> 4;

    // A fragments: k 0..127 from hn, 128..255 from agg
    bf16x8 a[8];
    const unsigned short* hrow = hnb + (size_t)(rbase + lrow) * 128 + lhi * 8;
    const unsigned short* arow = aggb + (size_t)(rbase + lrow) * 128 + lhi * 8;
    #pragma unroll
    for (int kc = 0; kc < 4; ++kc) a[kc]     = *(const bf16x8*)(hrow + kc * 32);
    #pragma unroll
    for (int kc = 0; kc < 4; ++kc) a[4 + kc] = *(const bf16x8*)(arow + kc * 32);

    f32x4 acc[8];
    #pragma unroll
    for (int ct = 0; ct < 8; ++ct) acc[ct] = (f32x4){0.f, 0.f, 0.f, 0.f};

    #pragma unroll
    for (int ct = 0; ct < 8; ++ct) {
        const unsigned short* bb = wlds + (ct * 16 + lrow) * 264 + lhi * 8;
        #pragma unroll
        for (int kc = 0; kc < 8; ++kc) {
            bf16x8 bfrag = *(const bf16x8*)(bb + kc * 32);
            acc[ct] = __builtin_amdgcn_mfma_f32_16x16x32_bf16(a[kc], bfrag, acc[ct], 0, 0, 0);
        }
    }

    // epilogue: D layout col=lane&15, row=(lane>>4)*4+i
    #pragma unroll
    for (int ct = 0; ct < 8; ++ct) {
        int col = ct * 16 + lrow;
        float bv = bias[col];
        #pragma unroll
        for (int i = 0; i < 4; ++i) {
            int row = rbase + lhi * 4 + i;
            out[(size_t)row * 128 + col] = acc[ct][i] + bv;
        }
    }
}

// ---------------------------------------------------------------------------
extern "C" void kernel_launch(void* const* d_in, const int* in_sizes, int n_in,
                              void* d_out, int out_size, void* d_ws, size_t ws_size,
                              hipStream_t stream) {
    const float* h     = (const float*)d_in[0];
    const void*  edges = d_in[1];
    const float* gamma = (const float*)d_in[2];
    const float* beta  = (const float*)d_in[3];
    const float* W     = (const float*)d_in[4];
    const float* bias  = (const float*)d_in[5];
    float* out = (float*)d_out;

    char* ws = (char*)d_ws;
    size_t off = 0;
    auto alloc = [&](size_t bytes) { size_t o = off; off += (bytes + 255) & ~(size_t)255; return o; };
    unsigned int* deg_out   = (unsigned int*)(ws + alloc((size_t)N_NODES * 4));
    unsigned int* deg_in    = (unsigned int*)(ws + alloc((size_t)N_NODES * 4));
    float*        inv_out   = (float*)(ws + alloc((size_t)N_NODES * 4));
    float*        inv_in    = (float*)(ws + alloc((size_t)N_NODES * 4));
    unsigned int* row_start = (unsigned int*)(ws + alloc((size_t)(N_NODES + 1) * 4));
    unsigned int* cursor    = (unsigned int*)(ws + alloc((size_t)N_NODES * 4));
    unsigned int* partials  = (unsigned int*)(ws + alloc(64 * 4));
    int*          flag      = (int*)(ws + alloc(16));
    unsigned int* Wb        = (unsigned int*)(ws + alloc((size_t)128 * 256 * 2));
    unsigned int* csr_src   = (unsigned int*)(ws + alloc((size_t)N_EDGES * 4));
    unsigned int* hnb       = (unsigned int*)(ws + alloc((size_t)N_NODES * D * 2));
    unsigned int* aggb      = (unsigned int*)(ws + alloc((size_t)N_NODES * D * 2));

    // zero deg_out + deg_in (first two 256-aligned regions, contiguous)
    size_t degpad = ((size_t)N_NODES * 4 + 255) & ~(size_t)255;
    hipMemsetAsync(ws, 0, 2 * degpad, stream);

    detect_idx64<<<1, 64, 0, stream>>>((const unsigned int*)edges, flag);
    deg_kernel<<<(N_EDGES + 255) / 256, 256, 0, stream>>>(edges, deg_out, deg_in, flag);
    inv_sqrt_kernel<<<(N_NODES + 255) / 256, 256, 0, stream>>>(deg_out, deg_in, inv_out, inv_in);
    scan1<<<(N_NODES + 1023) / 1024, 1024, 0, stream>>>(deg_in, row_start, partials);
    scan2<<<(N_NODES + 1023) / 1024, 1024, 0, stream>>>(partials, row_start, cursor);
    ln_kernel<<<(N_NODES + 3) / 4, 256, 0, stream>>>((const float2*)h, (const float2*)gamma,
                                                     (const float2*)beta, hnb);
    cast_W<<<64, 256, 0, stream>>>((const float2*)W, Wb);
    fill_csr<<<(N_EDGES + 255) / 256, 256, 0, stream>>>(edges, cursor, csr_src, flag);
    agg_kernel<<<(N_NODES + 3) / 4, 256, 0, stream>>>(hnb, inv_out, inv_in, row_start,
                                                      csr_src, aggb);
    gemm_kernel<<<(N_NODES + 63) / 64, 256, 0, stream>>>((const unsigned short*)hnb,
                                                         (const unsigned short*)aggb,
                                                         (const unsigned short*)Wb,
                                                         bias, out);
}

// Round 5
// 137.982 us; speedup vs baseline: 8.4813x; 1.2495x over previous
//
#include <hip/hip_runtime.h>
#include <stdint.h>

#define N_NODES 50000
#define N_EDGES 600000
#define D       128
#define EPS     1e-5f
#define HG      16          // partial-histogram blocks per index array
#define NWORDS  25000       // 50000 u16 counters packed in u32 words

typedef __attribute__((ext_vector_type(8))) short bf16x8;   // 8 bf16 = 4 VGPR
typedef __attribute__((ext_vector_type(4))) float f32x4;    // MFMA acc

__device__ __forceinline__ unsigned short f2bf(float x) {   // RNE f32->bf16
    unsigned int u = __float_as_uint(x);
    return (unsigned short)((u + 0x7fffu + ((u >> 16) & 1u)) >> 16);
}

// ---------------------------------------------------------------------------
// edge dtype detection (int64 vs int32), 64-lane ballot
// ---------------------------------------------------------------------------
__global__ void detect_idx64(const unsigned int* e, int* flag) {
    int lane = threadIdx.x & 63;
    unsigned int v = e[2 * lane + 1];
    unsigned long long nz = __ballot(v != 0u);
    if (threadIdx.x == 0) *flag = (nz == 0ull) ? 1 : 0;
}

__device__ __forceinline__ int load_idx(const void* e, long long i, int is64) {
    return is64 ? (int)((const long long*)e)[i] : ((const int*)e)[i];
}

// ---------------------------------------------------------------------------
// degree histograms via LDS (zero global atomics):
// 32 blocks x 1024 thr; blocks 0..15 count src, 16..31 count dst.
// Each block: full 50000-bin u16-packed histogram in 100 KB LDS over a
// 37.5k-edge slice (per-block bin count < 65536), flushed coalesced to
// partials[which][b][NWORDS].
// ---------------------------------------------------------------------------
__global__ __launch_bounds__(1024) void hist_kernel(const void* edges,
                                                    const int* flag,
                                                    unsigned int* __restrict__ partials) {
    __shared__ unsigned int lhist[NWORDS];
    int which = blockIdx.x >> 4;   // 0 = src (out-deg), 1 = dst (in-deg)
    int b     = blockIdx.x & 15;
    int is64  = *flag;
    for (int i = threadIdx.x; i < NWORDS; i += 1024) lhist[i] = 0u;
    __syncthreads();
    const int per = (N_EDGES + HG - 1) / HG;  // 37500
    int lo = b * per;
    int hi = lo + per; if (hi > N_EDGES) hi = N_EDGES;
    long long base = which ? (long long)N_EDGES : 0ll;
    for (int i = lo + threadIdx.x; i < hi; i += 1024) {
        int v = load_idx(edges, base + i, is64);
        atomicAdd(&lhist[v >> 1], (v & 1) ? (1u << 16) : 1u);
    }
    __syncthreads();
    unsigned int* dst = partials + ((size_t)which * HG + b) * NWORDS;
    for (int i = threadIdx.x; i < NWORDS; i += 1024) dst[i] = lhist[i];
}

// ---------------------------------------------------------------------------
// sum 16 partials per histogram, emit deg_in (u32, for scan) and
// inv_out/inv_in = rsqrt(max(deg,1)). One thread per packed word (2 nodes).
// ---------------------------------------------------------------------------
__global__ __launch_bounds__(256) void deg_reduce(const unsigned int* __restrict__ partials,
                                                  unsigned int* __restrict__ deg_in,
                                                  float* __restrict__ inv_out,
                                                  float* __restrict__ inv_in) {
    int w = blockIdx.x * 256 + threadIdx.x;
    if (w >= NWORDS) return;
    unsigned int o0 = 0, o1 = 0, d0 = 0, d1 = 0;
    #pragma unroll
    for (int b = 0; b < HG; ++b) {
        unsigned int p = partials[(size_t)b * NWORDS + w];
        o0 += p & 0xffffu; o1 += p >> 16;
    }
    #pragma unroll
    for (int b = 0; b < HG; ++b) {
        unsigned int p = partials[(size_t)(HG + b) * NWORDS + w];
        d0 += p & 0xffffu; d1 += p >> 16;
    }
    deg_in[2 * w]     = d0;
    deg_in[2 * w + 1] = d1;
    inv_out[2 * w]     = rsqrtf((float)(o0 > 1u ? o0 : 1u));
    inv_out[2 * w + 1] = rsqrtf((float)(o1 > 1u ? o1 : 1u));
    inv_in[2 * w]      = rsqrtf((float)(d0 > 1u ? d0 : 1u));
    inv_in[2 * w + 1]  = rsqrtf((float)(d1 > 1u ? d1 : 1u));
}

// ---------------------------------------------------------------------------
// two-phase multi-block exclusive scan of deg_in (49 blocks x 1024)
// ---------------------------------------------------------------------------
__global__ __launch_bounds__(1024) void scan1(const unsigned int* __restrict__ deg,
                                              unsigned int* __restrict__ row_start,
                                              unsigned int* __restrict__ partials) {
    __shared__ unsigned int wsum[16];
    int t = threadIdx.x, lane = t & 63, w = t >> 6;
    int i = blockIdx.x * 1024 + t;
    unsigned int v = (i < N_NODES) ? deg[i] : 0u;
    unsigned int x = v;
    #pragma unroll
    for (int off = 1; off < 64; off <<= 1) {
        unsigned int y = __shfl_up(x, off, 64);
        if (lane >= off) x += y;
    }
    if (lane == 63) wsum[w] = x;
    __syncthreads();
    if (w == 0) {
        unsigned int s = (lane < 16) ? wsum[lane] : 0u;
        #pragma unroll
        for (int off = 1; off < 16; off <<= 1) {
            unsigned int y = __shfl_up(s, off, 64);
            if (lane >= off) s += y;
        }
        if (lane < 16) wsum[lane] = s;
    }
    __syncthreads();
    unsigned int excl = (w ? wsum[w - 1] : 0u) + x - v;
    if (i < N_NODES) row_start[i] = excl;
    if (t == 1023) partials[blockIdx.x] = wsum[15];
}

__global__ __launch_bounds__(1024) void scan2(const unsigned int* __restrict__ partials,
                                              unsigned int* __restrict__ row_start,
                                              unsigned int* __restrict__ cursor) {
    __shared__ unsigned int soff;
    int t = threadIdx.x, b = blockIdx.x;
    if (t < 64) {
        unsigned int p = (t < b) ? partials[t] : 0u;   // b <= 48 < 64
        #pragma unroll
        for (int off = 32; off; off >>= 1) p += __shfl_xor(p, off, 64);
        if (t == 0) soff = p;
    }
    __syncthreads();
    int i = b * 1024 + t;
    if (i < N_NODES) {
        unsigned int r = row_start[i] + soff;
        row_start[i] = r;
        cursor[i]    = r;
    }
    if (b == 0 && t == 0) row_start[N_NODES] = N_EDGES;
}

// ---------------------------------------------------------------------------
// bucket fill: csr_src[pos] = src, bucketed by dst
// ---------------------------------------------------------------------------
__global__ __launch_bounds__(256) void fill_csr(const void* edges,
                                                unsigned int* cursor,
                                                unsigned int* csr_src,
                                                const int* flag) {
    int is64 = *flag;
    int i = blockIdx.x * blockDim.x + threadIdx.x;
    if (i < N_EDGES) {
        int s = load_idx(edges, i, is64);
        int d = load_idx(edges, (long long)N_EDGES + i, is64);
        unsigned int pos = atomicAdd(&cursor[d], 1u);
        csr_src[pos] = (unsigned int)s;
    }
}

// ---------------------------------------------------------------------------
// LayerNorm -> bf16 output (packed pairs). lane owns features 2l, 2l+1.
// ---------------------------------------------------------------------------
__global__ __launch_bounds__(256) void ln_kernel(const float2* __restrict__ h2,
                                                 const float2* __restrict__ g2,
                                                 const float2* __restrict__ b2,
                                                 unsigned int* __restrict__ hnb) {
    int wid  = threadIdx.x >> 6;
    int lane = threadIdx.x & 63;
    int row  = blockIdx.x * 4 + wid;
    if (row >= N_NODES) return;
    float2 v = h2[(size_t)row * 64 + lane];
    float s  = v.x + v.y;
    float ss = v.x * v.x + v.y * v.y;
    #pragma unroll
    for (int off = 32; off; off >>= 1) {
        s  += __shfl_xor(s,  off, 64);
        ss += __shfl_xor(ss, off, 64);
    }
    float mu  = s * (1.0f / D);
    float var = ss * (1.0f / D) - mu * mu;
    float rs  = rsqrtf(var + EPS);
    float2 g = g2[lane], b = b2[lane];
    float y0 = (v.x - mu) * rs * g.x + b.x;
    float y1 = (v.y - mu) * rs * g.y + b.y;
    hnb[(size_t)row * 64 + lane] = (unsigned int)f2bf(y0) | ((unsigned int)f2bf(y1) << 16);
}

// ---------------------------------------------------------------------------
// W f32 [128][256] -> bf16 packed (same layout)
// ---------------------------------------------------------------------------
__global__ __launch_bounds__(256) void cast_W(const float2* __restrict__ W2,
                                              unsigned int* __restrict__ Wb) {
    int i = blockIdx.x * 256 + threadIdx.x;
    if (i < 128 * 128) {
        float2 w = W2[i];
        Wb[i] = (unsigned int)f2bf(w.x) | ((unsigned int)f2bf(w.y) << 16);
    }
}

// ---------------------------------------------------------------------------
// aggregation: one wave per dst row; lane = packed bf16 feature pair (4 B)
// ---------------------------------------------------------------------------
__global__ __launch_bounds__(256) void agg_kernel(const unsigned int* __restrict__ hnb,
                                                  const float* __restrict__ inv_out,
                                                  const float* __restrict__ inv_in,
                                                  const unsigned int* __restrict__ row_start,
                                                  const unsigned int* __restrict__ csr_src,
                                                  unsigned int* __restrict__ aggb) {
    int wid  = threadIdx.x >> 6;
    int lane = threadIdx.x & 63;
    int row  = blockIdx.x * 4 + wid;
    if (row >= N_NODES) return;
    unsigned int e0 = row_start[row], e1 = row_start[row + 1];
    float ax = 0.0f, ay = 0.0f;
    unsigned int e = e0;
    while (e < e1) {
        unsigned int cnt = e1 - e;
        if (cnt > 64u) cnt = 64u;
        int sl = (lane < (int)cnt) ? (int)csr_src[e + lane] : 0;
        for (int i = 0; i < (int)cnt; ++i) {
            int s = __shfl(sl, i, 64);
            float sc = inv_out[s];
            unsigned int v = hnb[(size_t)s * 64 + lane];
            ax = fmaf(__uint_as_float(v << 16), sc, ax);
            ay = fmaf(__uint_as_float(v & 0xffff0000u), sc, ay);
        }
        e += cnt;
    }
    float ii = inv_in[row];
    aggb[(size_t)row * 64 + lane] =
        (unsigned int)f2bf(ax * ii) | ((unsigned int)f2bf(ay * ii) << 16);
}

// ---------------------------------------------------------------------------
// MFMA GEMM: out[50000][128] = cat([hn|agg]) @ W^T + b
// ---------------------------------------------------------------------------
__global__ __launch_bounds__(256) void gemm_kernel(const unsigned short* __restrict__ hnb,
                                                   const unsigned short* __restrict__ aggb,
                                                   const unsigned short* __restrict__ Wb,
                                                   const float* __restrict__ bias,
                                                   float* __restrict__ out) {
    __shared__ unsigned short wlds[128 * 264];
    int t = threadIdx.x;
    {
        int j = t >> 1, half = t & 1;
        const uint4* src = (const uint4*)(Wb + (size_t)j * 256 + half * 128);
        uint4* dst = (uint4*)(wlds + j * 264 + half * 128);
        #pragma unroll
        for (int i = 0; i < 16; ++i) dst[i] = src[i];
    }
    __syncthreads();

    int w = t >> 6, lane = t & 63;
    int rbase = blockIdx.x * 64 + w * 16;
    if (rbase >= N_NODES) return;
    int lrow = lane & 15, lhi = lane >> 4;

    bf16x8 a[8];
    const unsigned short* hrow = hnb + (size_t)(rbase + lrow) * 128 + lhi * 8;
    const unsigned short* arow = aggb + (size_t)(rbase + lrow) * 128 + lhi * 8;
    #pragma unroll
    for (int kc = 0; kc < 4; ++kc) a[kc]     = *(const bf16x8*)(hrow + kc * 32);
    #pragma unroll
    for (int kc = 0; kc < 4; ++kc) a[4 + kc] = *(const bf16x8*)(arow + kc * 32);

    f32x4 acc[8];
    #pragma unroll
    for (int ct = 0; ct < 8; ++ct) acc[ct] = (f32x4){0.f, 0.f, 0.f, 0.f};

    #pragma unroll
    for (int ct = 0; ct < 8; ++ct) {
        const unsigned short* bb = wlds + (ct * 16 + lrow) * 264 + lhi * 8;
        #pragma unroll
        for (int kc = 0; kc < 8; ++kc) {
            bf16x8 bfrag = *(const bf16x8*)(bb + kc * 32);
            acc[ct] = __builtin_amdgcn_mfma_f32_16x16x32_bf16(a[kc], bfrag, acc[ct], 0, 0, 0);
        }
    }

    #pragma unroll
    for (int ct = 0; ct < 8; ++ct) {
        int col = ct * 16 + lrow;
        float bv = bias[col];
        #pragma unroll
        for (int i = 0; i < 4; ++i) {
            int row = rbase + lhi * 4 + i;
            out[(size_t)row * 128 + col] = acc[ct][i] + bv;
        }
    }
}

// ---------------------------------------------------------------------------
extern "C" void kernel_launch(void* const* d_in, const int* in_sizes, int n_in,
                              void* d_out, int out_size, void* d_ws, size_t ws_size,
                              hipStream_t stream) {
    const float* h     = (const float*)d_in[0];
    const void*  edges = d_in[1];
    const float* gamma = (const float*)d_in[2];
    const float* beta  = (const float*)d_in[3];
    const float* W     = (const float*)d_in[4];
    const float* bias  = (const float*)d_in[5];
    float* out = (float*)d_out;

    char* ws = (char*)d_ws;
    size_t off = 0;
    auto alloc = [&](size_t bytes) { size_t o = off; off += (bytes + 255) & ~(size_t)255; return o; };
    unsigned int* hpart     = (unsigned int*)(ws + alloc((size_t)2 * HG * NWORDS * 4));
    unsigned int* deg_in    = (unsigned int*)(ws + alloc((size_t)N_NODES * 4));
    float*        inv_out   = (float*)(ws + alloc((size_t)N_NODES * 4));
    float*        inv_in    = (float*)(ws + alloc((size_t)N_NODES * 4));
    unsigned int* row_start = (unsigned int*)(ws + alloc((size_t)(N_NODES + 1) * 4));
    unsigned int* cursor    = (unsigned int*)(ws + alloc((size_t)N_NODES * 4));
    unsigned int* spart     = (unsigned int*)(ws + alloc(64 * 4));
    int*          flag      = (int*)(ws + alloc(16));
    unsigned int* Wb        = (unsigned int*)(ws + alloc((size_t)128 * 256 * 2));
    unsigned int* csr_src   = (unsigned int*)(ws + alloc((size_t)N_EDGES * 4));
    unsigned int* hnb       = (unsigned int*)(ws + alloc((size_t)N_NODES * D * 2));
    unsigned int* aggb      = (unsigned int*)(ws + alloc((size_t)N_NODES * D * 2));

    detect_idx64<<<1, 64, 0, stream>>>((const unsigned int*)edges, flag);
    hist_kernel<<<2 * HG, 1024, 0, stream>>>(edges, flag, hpart);
    deg_reduce<<<(NWORDS + 255) / 256, 256, 0, stream>>>(hpart, deg_in, inv_out, inv_in);
    scan1<<<(N_NODES + 1023) / 1024, 1024, 0, stream>>>(deg_in, row_start, spart);
    scan2<<<(N_NODES + 1023) / 1024, 1024, 0, stream>>>(spart, row_start, cursor);
    ln_kernel<<<(N_NODES + 3) / 4, 256, 0, stream>>>((const float2*)h, (const float2*)gamma,
                                                     (const float2*)beta, hnb);
    cast_W<<<64, 256, 0, stream>>>((const float2*)W, Wb);
    fill_csr<<<(N_EDGES + 255) / 256, 256, 0, stream>>>(edges, cursor, csr_src, flag);
    agg_kernel<<<(N_NODES + 3) / 4, 256, 0, stream>>>(hnb, inv_out, inv_in, row_start,
                                                      csr_src, aggb);
    gemm_kernel<<<(N_NODES + 63) / 64, 256, 0, stream>>>((const unsigned short*)hnb,
                                                         (const unsigned short*)aggb,
                                                         (const unsigned short*)Wb,
                                                         bias, out);
}

// Round 6
// 110.087 us; speedup vs baseline: 10.6304x; 1.2534x over previous
//
#include <hip/hip_runtime.h>
#include <stdint.h>

#define N_NODES 50000
#define N_EDGES 600000
#define D       128
#define EPS     1e-5f
#define HG      64          // slices per index array (600000/64 = 9375)
#define NWORDS  25000       // 50000 u16 counters packed in u32 words

typedef __attribute__((ext_vector_type(8))) short bf16x8;   // 8 bf16 = 4 VGPR
typedef __attribute__((ext_vector_type(4))) float f32x4;    // MFMA acc

__device__ __forceinline__ unsigned short f2bf(float x) {   // RNE f32->bf16
    unsigned int u = __float_as_uint(x);
    return (unsigned short)((u + 0x7fffu + ((u >> 16) & 1u)) >> 16);
}

__device__ __forceinline__ int load_idx(const void* e, long long i, int is64) {
    return is64 ? (int)((const long long*)e)[i] : ((const int*)e)[i];
}

// in-block edge dtype detect (wave 0): int64 => high words all zero
__device__ __forceinline__ int block_detect64(const unsigned int* eraw, int* sflag) {
    if (threadIdx.x < 64) {
        unsigned long long nz = __ballot(eraw[2 * threadIdx.x + 1] != 0u);
        if (threadIdx.x == 0) *sflag = (nz == 0ull) ? 1 : 0;
    }
    __syncthreads();
    return *sflag;
}

// ---------------------------------------------------------------------------
// degree histograms in LDS (zero global atomics):
// 2*HG blocks x 1024 thr; blocks [0,HG) count src, [HG,2HG) count dst,
// each over a 9375-edge slice. Full 50000-bin u16-packed hist in 100 KB LDS.
// ---------------------------------------------------------------------------
__global__ __launch_bounds__(1024) void hist_kernel(const unsigned int* __restrict__ eraw,
                                                    unsigned int* __restrict__ partials) {
    __shared__ unsigned int lhist[NWORDS];
    __shared__ int sflag;
    int t = threadIdx.x;
    int which = blockIdx.x >= HG;
    int b     = blockIdx.x & (HG - 1);
    for (int i = t; i < NWORDS; i += 1024) lhist[i] = 0u;
    int is64 = block_detect64(eraw, &sflag);   // includes __syncthreads
    const int per = N_EDGES / HG;
    int lo = b * per, hi = lo + per;
    long long base = which ? (long long)N_EDGES : 0ll;
    for (int i = lo + t; i < hi; i += 1024) {
        int v = load_idx(eraw, base + i, is64);
        atomicAdd(&lhist[v >> 1], (v & 1) ? (1u << 16) : 1u);
    }
    __syncthreads();
    unsigned int* dst = partials + (size_t)blockIdx.x * NWORDS;
    for (int i = t; i < NWORDS; i += 1024) dst[i] = lhist[i];
}

// ---------------------------------------------------------------------------
// sum per-slice partials -> deg_in (u32) + inv_out/inv_in = rsqrt(max(deg,1))
// ---------------------------------------------------------------------------
__global__ __launch_bounds__(256) void deg_reduce(const unsigned int* __restrict__ partials,
                                                  unsigned int* __restrict__ deg_in,
                                                  float* __restrict__ inv_out,
                                                  float* __restrict__ inv_in) {
    int w = blockIdx.x * 256 + threadIdx.x;
    if (w >= NWORDS) return;
    unsigned int o0 = 0, o1 = 0, d0 = 0, d1 = 0;
    for (int b = 0; b < HG; ++b) {
        unsigned int p = partials[(size_t)b * NWORDS + w];
        o0 += p & 0xffffu; o1 += p >> 16;
    }
    for (int b = 0; b < HG; ++b) {
        unsigned int p = partials[(size_t)(HG + b) * NWORDS + w];
        d0 += p & 0xffffu; d1 += p >> 16;
    }
    deg_in[2 * w]     = d0;
    deg_in[2 * w + 1] = d1;
    inv_out[2 * w]     = rsqrtf((float)(o0 > 1u ? o0 : 1u));
    inv_out[2 * w + 1] = rsqrtf((float)(o1 > 1u ? o1 : 1u));
    inv_in[2 * w]      = rsqrtf((float)(d0 > 1u ? d0 : 1u));
    inv_in[2 * w + 1]  = rsqrtf((float)(d1 > 1u ? d1 : 1u));
}

// ---------------------------------------------------------------------------
// two-phase multi-block exclusive scan of deg_in -> row_start
// ---------------------------------------------------------------------------
__global__ __launch_bounds__(1024) void scan1(const unsigned int* __restrict__ deg,
                                              unsigned int* __restrict__ row_start,
                                              unsigned int* __restrict__ partials) {
    __shared__ unsigned int wsum[16];
    int t = threadIdx.x, lane = t & 63, w = t >> 6;
    int i = blockIdx.x * 1024 + t;
    unsigned int v = (i < N_NODES) ? deg[i] : 0u;
    unsigned int x = v;
    #pragma unroll
    for (int off = 1; off < 64; off <<= 1) {
        unsigned int y = __shfl_up(x, off, 64);
        if (lane >= off) x += y;
    }
    if (lane == 63) wsum[w] = x;
    __syncthreads();
    if (w == 0) {
        unsigned int s = (lane < 16) ? wsum[lane] : 0u;
        #pragma unroll
        for (int off = 1; off < 16; off <<= 1) {
            unsigned int y = __shfl_up(s, off, 64);
            if (lane >= off) s += y;
        }
        if (lane < 16) wsum[lane] = s;
    }
    __syncthreads();
    unsigned int excl = (w ? wsum[w - 1] : 0u) + x - v;
    if (i < N_NODES) row_start[i] = excl;
    if (t == 1023) partials[blockIdx.x] = wsum[15];
}

__global__ __launch_bounds__(1024) void scan2(const unsigned int* __restrict__ partials,
                                              unsigned int* __restrict__ row_start) {
    __shared__ unsigned int soff;
    int t = threadIdx.x, b = blockIdx.x;
    if (t < 64) {
        unsigned int p = (t < b) ? partials[t] : 0u;   // b <= 48 < 64
        #pragma unroll
        for (int off = 32; off; off >>= 1) p += __shfl_xor(p, off, 64);
        if (t == 0) soff = p;
    }
    __syncthreads();
    int i = b * 1024 + t;
    if (i < N_NODES) row_start[i] += soff;
    if (b == 0 && t == 0) row_start[N_NODES] = N_EDGES;
}

// ---------------------------------------------------------------------------
// pre[b][v] = row_start[v] + sum_{b'<b} dst_partial[b'][v]
// ---------------------------------------------------------------------------
__global__ __launch_bounds__(256) void prefix_kernel(const unsigned int* __restrict__ partials,
                                                     const unsigned int* __restrict__ row_start,
                                                     unsigned int* __restrict__ pre) {
    int w = blockIdx.x * 256 + threadIdx.x;
    if (w >= NWORDS) return;
    unsigned int run0 = row_start[2 * w], run1 = row_start[2 * w + 1];
    for (int b = 0; b < HG; ++b) {
        pre[(size_t)b * N_NODES + 2 * w]     = run0;
        pre[(size_t)b * N_NODES + 2 * w + 1] = run1;
        unsigned int p = partials[(size_t)(HG + b) * NWORDS + w];
        run0 += p & 0xffffu; run1 += p >> 16;
    }
}

// ---------------------------------------------------------------------------
// atomic-free CSR fill: block b handles slice b with LDS packed-u16 cursors;
// csr_src[pre[b][d] + local_pos] = s
// ---------------------------------------------------------------------------
__global__ __launch_bounds__(1024) void fill_kernel(const unsigned int* __restrict__ eraw,
                                                    const unsigned int* __restrict__ pre,
                                                    unsigned int* __restrict__ csr_src) {
    __shared__ unsigned int lcur[NWORDS];
    __shared__ int sflag;
    int t = threadIdx.x, b = blockIdx.x;
    for (int i = t; i < NWORDS; i += 1024) lcur[i] = 0u;
    int is64 = block_detect64(eraw, &sflag);
    const int per = N_EDGES / HG;
    int lo = b * per, hi = lo + per;
    const unsigned int* preb = pre + (size_t)b * N_NODES;
    for (int i = lo + t; i < hi; i += 1024) {
        int s = load_idx(eraw, i, is64);
        int d = load_idx(eraw, (long long)N_EDGES + i, is64);
        unsigned int old = atomicAdd(&lcur[d >> 1], (d & 1) ? (1u << 16) : 1u);
        unsigned int pl = (d & 1) ? (old >> 16) : (old & 0xffffu);
        csr_src[preb[d] + pl] = (unsigned int)s;
    }
}

// ---------------------------------------------------------------------------
// LayerNorm -> bf16 packed pairs
// ---------------------------------------------------------------------------
__global__ __launch_bounds__(256) void ln_kernel(const float2* __restrict__ h2,
                                                 const float2* __restrict__ g2,
                                                 const float2* __restrict__ b2,
                                                 unsigned int* __restrict__ hnb) {
    int wid  = threadIdx.x >> 6;
    int lane = threadIdx.x & 63;
    int row  = blockIdx.x * 4 + wid;
    if (row >= N_NODES) return;
    float2 v = h2[(size_t)row * 64 + lane];
    float s  = v.x + v.y;
    float ss = v.x * v.x + v.y * v.y;
    #pragma unroll
    for (int off = 32; off; off >>= 1) {
        s  += __shfl_xor(s,  off, 64);
        ss += __shfl_xor(ss, off, 64);
    }
    float mu  = s * (1.0f / D);
    float var = ss * (1.0f / D) - mu * mu;
    float rs  = rsqrtf(var + EPS);
    float2 g = g2[lane], b = b2[lane];
    float y0 = (v.x - mu) * rs * g.x + b.x;
    float y1 = (v.y - mu) * rs * g.y + b.y;
    hnb[(size_t)row * 64 + lane] = (unsigned int)f2bf(y0) | ((unsigned int)f2bf(y1) << 16);
}

// ---------------------------------------------------------------------------
// W f32 [128][256] -> bf16 packed
// ---------------------------------------------------------------------------
__global__ __launch_bounds__(256) void cast_W(const float2* __restrict__ W2,
                                              unsigned int* __restrict__ Wb) {
    int i = blockIdx.x * 256 + threadIdx.x;
    if (i < 128 * 128) {
        float2 w = W2[i];
        Wb[i] = (unsigned int)f2bf(w.x) | ((unsigned int)f2bf(w.y) << 16);
    }
}

// ---------------------------------------------------------------------------
// aggregation: one wave per dst row; 4 x 16-lane groups process 4 edges
// concurrently, 16 B (8 features) per lane; cross-group shfl reduce at end.
// ---------------------------------------------------------------------------
__global__ __launch_bounds__(256) void agg_kernel(const unsigned int* __restrict__ hnb,
                                                  const float* __restrict__ inv_out,
                                                  const float* __restrict__ inv_in,
                                                  const unsigned int* __restrict__ row_start,
                                                  const unsigned int* __restrict__ csr_src,
                                                  unsigned int* __restrict__ aggb) {
    int wid  = threadIdx.x >> 6;
    int lane = threadIdx.x & 63;
    int row  = blockIdx.x * 4 + wid;
    if (row >= N_NODES) return;
    int g = lane >> 4, gl = lane & 15;
    unsigned int e0 = row_start[row], e1 = row_start[row + 1];
    float acc[8];
    #pragma unroll
    for (int j = 0; j < 8; ++j) acc[j] = 0.0f;

    unsigned int e = e0;
    while (e < e1) {
        unsigned int cnt = e1 - e;
        if (cnt > 64u) cnt = 64u;
        int sl = (lane < (int)cnt) ? (int)csr_src[e + lane] : 0;
        int nit = ((int)cnt + 3) >> 2;
        for (int it = 0; it < nit; ++it) {
            int idx = it * 4 + g;
            int s = __shfl(sl, idx, 64);       // per-lane src (uniform in group)
            if (idx < (int)cnt) {
                float sc = inv_out[s];
                uint4 v = *(const uint4*)(hnb + (size_t)s * 64 + gl * 4);
                acc[0] = fmaf(__uint_as_float(v.x << 16),          sc, acc[0]);
                acc[1] = fmaf(__uint_as_float(v.x & 0xffff0000u),  sc, acc[1]);
                acc[2] = fmaf(__uint_as_float(v.y << 16),          sc, acc[2]);
                acc[3] = fmaf(__uint_as_float(v.y & 0xffff0000u),  sc, acc[3]);
                acc[4] = fmaf(__uint_as_float(v.z << 16),          sc, acc[4]);
                acc[5] = fmaf(__uint_as_float(v.z & 0xffff0000u),  sc, acc[5]);
                acc[6] = fmaf(__uint_as_float(v.w << 16),          sc, acc[6]);
                acc[7] = fmaf(__uint_as_float(v.w & 0xffff0000u),  sc, acc[7]);
            }
        }
        e += cnt;
    }
    // combine the 4 groups (lanes with equal gl)
    #pragma unroll
    for (int j = 0; j < 8; ++j) {
        acc[j] += __shfl_xor(acc[j], 16, 64);
        acc[j] += __shfl_xor(acc[j], 32, 64);
    }
    if (g == 0) {
        float ii = inv_in[row];
        uint4 o;
        o.x = (unsigned int)f2bf(acc[0] * ii) | ((unsigned int)f2bf(acc[1] * ii) << 16);
        o.y = (unsigned int)f2bf(acc[2] * ii) | ((unsigned int)f2bf(acc[3] * ii) << 16);
        o.z = (unsigned int)f2bf(acc[4] * ii) | ((unsigned int)f2bf(acc[5] * ii) << 16);
        o.w = (unsigned int)f2bf(acc[6] * ii) | ((unsigned int)f2bf(acc[7] * ii) << 16);
        *(uint4*)(aggb + (size_t)row * 64 + gl * 4) = o;
    }
}

// ---------------------------------------------------------------------------
// MFMA GEMM: out[50000][128] = cat([hn|agg]) @ W^T + b
// ---------------------------------------------------------------------------
__global__ __launch_bounds__(256) void gemm_kernel(const unsigned short* __restrict__ hnb,
                                                   const unsigned short* __restrict__ aggb,
                                                   const unsigned short* __restrict__ Wb,
                                                   const float* __restrict__ bias,
                                                   float* __restrict__ out) {
    __shared__ unsigned short wlds[128 * 264];
    int t = threadIdx.x;
    {
        int j = t >> 1, half = t & 1;
        const uint4* src = (const uint4*)(Wb + (size_t)j * 256 + half * 128);
        uint4* dst = (uint4*)(wlds + j * 264 + half * 128);
        #pragma unroll
        for (int i = 0; i < 16; ++i) dst[i] = src[i];
    }
    __syncthreads();

    int w = t >> 6, lane = t & 63;
    int rbase = blockIdx.x * 64 + w * 16;
    if (rbase >= N_NODES) return;
    int lrow = lane & 15, lhi = lane >> 4;

    bf16x8 a[8];
    const unsigned short* hrow = hnb + (size_t)(rbase + lrow) * 128 + lhi * 8;
    const unsigned short* arow = aggb + (size_t)(rbase + lrow) * 128 + lhi * 8;
    #pragma unroll
    for (int kc = 0; kc < 4; ++kc) a[kc]     = *(const bf16x8*)(hrow + kc * 32);
    #pragma unroll
    for (int kc = 0; kc < 4; ++kc) a[4 + kc] = *(const bf16x8*)(arow + kc * 32);

    f32x4 acc[8];
    #pragma unroll
    for (int ct = 0; ct < 8; ++ct) acc[ct] = (f32x4){0.f, 0.f, 0.f, 0.f};

    #pragma unroll
    for (int ct = 0; ct < 8; ++ct) {
        const unsigned short* bb = wlds + (ct * 16 + lrow) * 264 + lhi * 8;
        #pragma unroll
        for (int kc = 0; kc < 8; ++kc) {
            bf16x8 bfrag = *(const bf16x8*)(bb + kc * 32);
            acc[ct] = __builtin_amdgcn_mfma_f32_16x16x32_bf16(a[kc], bfrag, acc[ct], 0, 0, 0);
        }
    }

    #pragma unroll
    for (int ct = 0; ct < 8; ++ct) {
        int col = ct * 16 + lrow;
        float bv = bias[col];
        #pragma unroll
        for (int i = 0; i < 4; ++i) {
            int row = rbase + lhi * 4 + i;
            out[(size_t)row * 128 + col] = acc[ct][i] + bv;
        }
    }
}

// ---------------------------------------------------------------------------
extern "C" void kernel_launch(void* const* d_in, const int* in_sizes, int n_in,
                              void* d_out, int out_size, void* d_ws, size_t ws_size,
                              hipStream_t stream) {
    const float* h     = (const float*)d_in[0];
    const unsigned int* eraw = (const unsigned int*)d_in[1];
    const float* gamma = (const float*)d_in[2];
    const float* beta  = (const float*)d_in[3];
    const float* W     = (const float*)d_in[4];
    const float* bias  = (const float*)d_in[5];
    float* out = (float*)d_out;

    char* ws = (char*)d_ws;
    size_t off = 0;
    auto alloc = [&](size_t bytes) { size_t o = off; off += (bytes + 255) & ~(size_t)255; return o; };
    unsigned int* hpart     = (unsigned int*)(ws + alloc((size_t)2 * HG * NWORDS * 4)); // 12.8 MB
    unsigned int* pre       = (unsigned int*)(ws + alloc((size_t)HG * N_NODES * 4));    // 12.8 MB
    unsigned int* deg_in    = (unsigned int*)(ws + alloc((size_t)N_NODES * 4));
    float*        inv_out   = (float*)(ws + alloc((size_t)N_NODES * 4));
    float*        inv_in    = (float*)(ws + alloc((size_t)N_NODES * 4));
    unsigned int* row_start = (unsigned int*)(ws + alloc((size_t)(N_NODES + 1) * 4));
    unsigned int* spart     = (unsigned int*)(ws + alloc(64 * 4));
    unsigned int* Wb        = (unsigned int*)(ws + alloc((size_t)128 * 256 * 2));
    unsigned int* csr_src   = (unsigned int*)(ws + alloc((size_t)N_EDGES * 4));
    unsigned int* hnb       = (unsigned int*)(ws + alloc((size_t)N_NODES * D * 2));
    unsigned int* aggb      = (unsigned int*)(ws + alloc((size_t)N_NODES * D * 2));

    hist_kernel<<<2 * HG, 1024, 0, stream>>>(eraw, hpart);
    ln_kernel<<<(N_NODES + 3) / 4, 256, 0, stream>>>((const float2*)h, (const float2*)gamma,
                                                     (const float2*)beta, hnb);
    deg_reduce<<<(NWORDS + 255) / 256, 256, 0, stream>>>(hpart, deg_in, inv_out, inv_in);
    scan1<<<(N_NODES + 1023) / 1024, 1024, 0, stream>>>(deg_in, row_start, spart);
    scan2<<<(N_NODES + 1023) / 1024, 1024, 0, stream>>>(spart, row_start);
    prefix_kernel<<<(NWORDS + 255) / 256, 256, 0, stream>>>(hpart, row_start, pre);
    cast_W<<<64, 256, 0, stream>>>((const float2*)W, Wb);
    fill_kernel<<<HG, 1024, 0, stream>>>(eraw, pre, csr_src);
    agg_kernel<<<(N_NODES + 3) / 4, 256, 0, stream>>>(hnb, inv_out, inv_in, row_start,
                                                      csr_src, aggb);
    gemm_kernel<<<(N_NODES + 63) / 64, 256, 0, stream>>>((const unsigned short*)hnb,
                                                         (const unsigned short*)aggb,
                                                         (const unsigned short*)Wb,
                                                         bias, out);
}